// Round 9
// baseline (257.436 us; speedup 1.0000x reference)
//
#include <hip/hip_runtime.h>
#include <hip/hip_bf16.h>

#define DD 256
#define CC 104
#define NSL 8      // feature slices: 8 x 32 dims (64B) — one slice per XCD

typedef __bf16 bf16x8 __attribute__((ext_vector_type(8)));
typedef float  f32x4  __attribute__((ext_vector_type(4)));
typedef unsigned u32x2 __attribute__((ext_vector_type(2)));

__device__ inline float bu2f(unsigned short u) {
    return __uint_as_float(((unsigned)u) << 16);
}
__device__ inline unsigned short f2bu(float f) {
    __hip_bfloat16 h = __float2bfloat16(f);
    return *reinterpret_cast<unsigned short*>(&h);
}

// ---------------------------------------------------------------------------
// Kernel 1: prep — per-edge packed meta + W,Wc -> bf16 fragment order.
// etp[e] = token(16b) | (dst&15)<<16 | is_last<<20.  Groups of 16 dsts are
// 16-ALIGNED, so dst&15 is the group-local dst index (mask-MFMA needs it).
// ---------------------------------------------------------------------------
__global__ void prep_all(
    const int* __restrict__ token_id,
    const int* __restrict__ src_idx,
    const int* __restrict__ dst_idx,
    int* __restrict__ seg_start,
    int* __restrict__ seg_end,
    int* __restrict__ etp,
    int* __restrict__ last_tok,
    int E, int PB,
    const float* __restrict__ W,
    const float* __restrict__ Wc,
    __hip_bfloat16* __restrict__ Wfrag,
    __hip_bfloat16* __restrict__ Wcfrag)
{
    const int b = blockIdx.x;
    const int t = threadIdx.x;
    if (b < PB) {
        int e = b * 256 + t;
        if (e >= E) return;
        int d = dst_idx[e];
        int tok = token_id[src_idx[e]];
        int lastf = (e == E - 1 || dst_idx[e + 1] != d) ? 1 : 0;
        etp[e] = tok | ((d & 15) << 16) | (lastf << 20);
        if (e == 0 || dst_idx[e - 1] != d) seg_start[d] = e;
        if (lastf) { seg_end[d] = e + 1; last_tok[d] = tok; }
        return;
    }
    if (b < PB + 32) {                      // W fragment reorder
        int idx  = (b - PB) * 256 + t;      // 0..8191
        int lane = idx & 63, g = idx >> 6;  // g = k0*16 + nt
        int nt = g & 15, k0 = g >> 4;
        int r = nt * 16 + (lane & 15);
        int c = k0 * 32 + (lane >> 4) * 8;
        const float* src = W + (size_t)r * DD + c;
        float4 v0 = *(const float4*)(src);
        float4 v1 = *(const float4*)(src + 4);
        uint4 pk;
        pk.x = (unsigned)f2bu(v0.x) | ((unsigned)f2bu(v0.y) << 16);
        pk.y = (unsigned)f2bu(v0.z) | ((unsigned)f2bu(v0.w) << 16);
        pk.z = (unsigned)f2bu(v1.x) | ((unsigned)f2bu(v1.y) << 16);
        pk.w = (unsigned)f2bu(v1.z) | ((unsigned)f2bu(v1.w) << 16);
        *(uint4*)(Wfrag + (size_t)idx * 8) = pk;
        return;
    }
    {                                       // Wc fragment reorder (padded)
        int idx  = (b - PB - 32) * 256 + t; // 0..4095
        int lane = idx & 63, g = idx >> 6;  // g = k0*8 + nt
        int nt = g & 7, k0 = g >> 3;
        int r = nt * 16 + (lane & 15);      // 0..127
        int c = k0 * 32 + (lane >> 4) * 8;
        float4 v0 = make_float4(0.f,0.f,0.f,0.f);
        float4 v1 = make_float4(0.f,0.f,0.f,0.f);
        if (r < CC) {
            const float* src = Wc + (size_t)r * DD + c;
            v0 = *(const float4*)(src);
            v1 = *(const float4*)(src + 4);
        }
        uint4 pk;
        pk.x = (unsigned)f2bu(v0.x) | ((unsigned)f2bu(v0.y) << 16);
        pk.y = (unsigned)f2bu(v0.z) | ((unsigned)f2bu(v0.w) << 16);
        pk.z = (unsigned)f2bu(v1.x) | ((unsigned)f2bu(v1.y) << 16);
        pk.w = (unsigned)f2bu(v1.z) | ((unsigned)f2bu(v1.w) << 16);
        *(uint4*)(Wcfrag + (size_t)idx * 8) = pk;
    }
}

// ---------------------------------------------------------------------------
// Kernel 1b (R16): mask_build — precompute the B-fragments (masks).
// The mask is slice-independent edge metadata; R14/R15 rebuilt it with ~25
// VALU per round in EVERY slice-wave (8x redundant) — half the seg kernel's
// issue budget. Build once per (group, round): slot rb_g + r where
// rb_g = (S_g>>5) + g.  Non-overlap proof: R_g = ceil((S_{g+1}-S_g)/32)
// <= (S_{g+1}>>5) - (S_g>>5) + 1  =>  rb_g + R_g <= rb_{g+1}.
// Layout: maskbuf[slot*64 + lane] = uint4 B-frag (lane l: [n=l&15][k=kb+j]).
// ---------------------------------------------------------------------------
__global__ __launch_bounds__(256, 8) void mask_build(
    const int* __restrict__ etp,
    const int* __restrict__ seg_start,
    const int* __restrict__ seg_end,
    uint4* __restrict__ maskbuf,
    int n_dst)
{
    const int g  = blockIdx.x;
    const int wv = threadIdx.x >> 6;
    const int l  = threadIdx.x & 63;
    const int l15 = l & 15;
    const int kb  = (l >> 4) * 8;
    const int d0 = g * 16;
    if (d0 >= n_dst) return;
    const int d1  = min(d0 + 16, n_dst);
    const int S   = seg_start[d0];
    const int End = seg_end[d1 - 1];
    const int R   = (End - S + 31) >> 5;
    const int rb  = (S >> 5) + g;
    for (int r = wv; r < R; r += 4) {
        int ebase = S + 32 * r + kb;
        unsigned mw[4] = {0u, 0u, 0u, 0u};
#pragma unroll
        for (int j = 0; j < 8; ++j) {
            int e  = ebase + j;
            int ec = min(e, End - 1);
            int m  = etp[ec];
            bool match = (e < End) && !((m >> 20) & 1)
                       && (((m >> 16) & 15) == l15);
            if (match) mw[j >> 1] |= (j & 1) ? 0x3F800000u : 0x3F80u;
        }
        maskbuf[(size_t)(rb + r) * 64 + l] = make_uint4(mw[0], mw[1], mw[2], mw[3]);
    }
}

// ---------------------------------------------------------------------------
// Kernel 2: We = emb @ W^T for ALL tokens (dense streaming MFMA GEMM).
// Webuf and embb written SLICE-MAJOR: [slice=dim/32][V][32 dims] so each
// XCD's L2 can keep exactly its 3.2MB slice resident during the gather.
// ---------------------------------------------------------------------------
__global__ __launch_bounds__(256, 3) void we_gemm(
    const float* __restrict__ emb,             // [V,256] fp32
    const __hip_bfloat16* __restrict__ Wfrag,  // 128 groups x 512
    __hip_bfloat16* __restrict__ Webuf,        // [8][V][32] bf16 out
    __hip_bfloat16* __restrict__ embb,         // [8][V][32] bf16 out
    int V)
{
    __shared__ __hip_bfloat16 lds[32 * 512];   // 32KB
    const int t    = threadIdx.x;
    const int lane = t & 63;
    const int w    = t >> 6;
    const int quad = lane >> 4;
    const int l16  = lane & 15;
    const int mrow = blockIdx.x * 64 + w * 16 + l16;
    const int row  = min(mrow, V - 1);

    // stream emb row fp32 -> bf16 frags (+ embb slice-major side-write)
    bf16x8 bfrag[8];
#pragma unroll
    for (int k0 = 0; k0 < 8; ++k0) {
        const float* src = emb + (size_t)row * DD + k0 * 32 + quad * 8;
        float4 v0 = *(const float4*)(src);
        float4 v1 = *(const float4*)(src + 4);
        uint4 pk;
        pk.x = (unsigned)f2bu(v0.x) | ((unsigned)f2bu(v0.y) << 16);
        pk.y = (unsigned)f2bu(v0.z) | ((unsigned)f2bu(v0.w) << 16);
        pk.z = (unsigned)f2bu(v1.x) | ((unsigned)f2bu(v1.y) << 16);
        pk.w = (unsigned)f2bu(v1.z) | ((unsigned)f2bu(v1.w) << 16);
        bfrag[k0] = *(bf16x8*)&pk;
        if (mrow < V)   // slice k0, chunk quad*8 within slice
            *(uint4*)(embb + (size_t)k0 * V * 32 + (size_t)row * 32 + quad * 8) = pk;
    }

    f32x4 acc[16];
#pragma unroll
    for (int nt = 0; nt < 16; ++nt) acc[nt] = (f32x4){0.f,0.f,0.f,0.f};

    for (int p = 0; p < 4; ++p) {
        if (p) __syncthreads();
        // straight-copy groups [32p, 32p+32): 32KB
#pragma unroll
        for (int it = 0; it < 8; ++it) {
            int idx = it * 256 + t;
            *(uint4*)(lds + (size_t)idx * 8) =
                *(const uint4*)(Wfrag + (size_t)p * 16384 + (size_t)idx * 8);
        }
        __syncthreads();
#pragma unroll
        for (int kl = 0; kl < 2; ++kl) {
            int k0 = p * 2 + kl;
#pragma unroll
            for (int nt = 0; nt < 16; ++nt) {
                bf16x8 wf = *(const bf16x8*)(lds + (kl * 16 + nt) * 512 + lane * 8);
                acc[nt] = __builtin_amdgcn_mfma_f32_16x16x32_bf16(wf, bfrag[k0], acc[nt], 0, 0, 0);
            }
        }
    }

    if (mrow < V) {
#pragma unroll
        for (int nt = 0; nt < 16; ++nt) {
            int c0 = nt * 16 + quad * 4;    // starting dim of this 4-dim piece
            ushort4 o;
            o.x = f2bu(acc[nt][0]);
            o.y = f2bu(acc[nt][1]);
            o.z = f2bu(acc[nt][2]);
            o.w = f2bu(acc[nt][3]);
            *(ushort4*)(Webuf + (size_t)(c0 >> 5) * V * 32 +
                        (size_t)mrow * 32 + (c0 & 31)) = o;
        }
    }
}

// ---------------------------------------------------------------------------
// Kernel 3 (R16): mask-MFMA segment sum, PRECOMPUTED MASKS.
// R8-R15 ledger: 8 structures, all 52-56us. Arithmetic rules out HW walls
// (TA line floor ~10us, L2 stream ~12us, HBM ~10us, MFMA ~3us) -> the
// invariant cost is ISSUE: ~140cy/round (25 VALU mask rebuild + 8 LDS ops
// + 3 VMEM + 2 MFMA + addr) x 200K wave-rounds / 256 CU ~ 45us = measured.
// R16 removes the mask rebuild (precomputed by mask_build, loaded as ONE
// nontemporal 16B/lane read — nt so the stream doesn't evict the Webuf
// slice from L2) and the ldsC code path. Round skeleton: etp + 2 gathers +
// 1 mask load + 2 ds_write_b128 + 4 tr reads + 2 MFMA (~75cy).
// Keeps R15's proven dbuf + ds_read_b64_tr_b16 (sigma perm) verbatim.
// ---------------------------------------------------------------------------
__global__ __launch_bounds__(256, 4) void seg_mfma(
    const __hip_bfloat16* __restrict__ Webuf,   // [8][V][32]
    const __hip_bfloat16* __restrict__ embb,    // [8][V][32]
    const int* __restrict__ etp,                // tok | loc<<16 | last<<20
    const int* __restrict__ seg_start,
    const int* __restrict__ seg_end,
    const int* __restrict__ last_tok,
    const uint4* __restrict__ maskbuf,          // [slots][64] B-frags
    const float* __restrict__ bvec,
    __hip_bfloat16* __restrict__ ftb,           // [8][n_dst][32]
    int n_dst, int V)
{
    // per wave, per buf: [half][p][16 rows][32B] = 2KB; two bufs
    __shared__ unsigned char ldsT[4][2][2048];
    const int t   = threadIdx.x;
    const int wv  = t >> 6;
    const int l   = t & 63;
    const int sl  = blockIdx.x & 7;               // slice == XCD (round-robin)
    const int g   = (blockIdx.x >> 3) * 4 + wv;   // 16-dst group
    const int d0  = g * 16;
    if (d0 >= n_dst) return;                      // wave-uniform, no barriers
    const int d1  = min(d0 + 16, n_dst);
    const int S   = seg_start[d0];
    const int End = seg_end[d1 - 1];              // segments tile [0,E)
    const int rb  = (S >> 5) + g;                 // mask slot base
    const int l15 = l & 15;
    const int k   = l >> 1;                       // my edge slot (pairs)
    const int half= l & 1;                        // my dim-half (16 dims)
    // stager target: subtile p, row rho (sigma permutation for tr reads)
    const int sp   = (k >> 2) & 1;
    const int srho = ((k >> 3) << 2) | (k & 3);
    const unsigned woff  = (unsigned)(half * 1024 + sp * 512 + srho * 32);
    const unsigned troff = (unsigned)(((l >> 4) << 7) + (l15 << 3));
    const __hip_bfloat16* wsl = Webuf + (size_t)sl * V * 32;
    const __hip_bfloat16* esl = embb  + (size_t)sl * V * 32;

    f32x4 acc0 = {0.f,0.f,0.f,0.f};
    f32x4 acc1 = {0.f,0.f,0.f,0.f};
    const int R = (End - S + 31) >> 5;
    const int rmax = R - 1;

    uint4 Q0, Q1;
    auto GATHER = [&](int r, uint4& A0, uint4& A1) {
        int e  = S + 32 * r + k;
        int ec = min(e, End - 1);
        int m  = etp[ec];
        int tok = m & 0xFFFF;
        const __hip_bfloat16* src = wsl + (size_t)tok * 32 + half * 16;
        A0 = *(const uint4*)(src);
        A1 = *(const uint4*)(src + 8);
    };
    auto WRITE = [&](int buf, const uint4& A0, const uint4& A1) {
        unsigned char* mb = &ldsT[wv][buf][0];
        *(uint4*)(mb + woff)      = A0;
        *(uint4*)(mb + woff + 16) = A1;
    };
    auto MLOAD = [&](int r) -> uint4 {
        const unsigned long long* mp =
            (const unsigned long long*)(maskbuf + ((size_t)(rb + r) << 6) + l);
        unsigned long long m0 = __builtin_nontemporal_load(mp);
        unsigned long long m1 = __builtin_nontemporal_load(mp + 1);
        uint4 q;
        ((unsigned long long*)&q)[0] = m0;
        ((unsigned long long*)&q)[1] = m1;
        return q;
    };

    // prologue: stage round 0 into buf 0; load mask 0
    GATHER(0, Q0, Q1);
    WRITE(0, Q0, Q1);
    uint4 mq = MLOAD(0);

    for (int r = 0; r < R; ++r) {
        // issue next round's gathers + mask early (last iter: L1-hit re-reads)
        int rn = min(r + 1, rmax);
        GATHER(rn, Q0, Q1);
        uint4 mqn = MLOAD(rn);
        __builtin_amdgcn_sched_barrier(0);   // keep loads above the compute

        // ---- compute round r from buf r&1 ----
        const int buf = r & 1;
        bf16x8 bm = *(bf16x8*)&mq;
        unsigned base = (unsigned)(uintptr_t)&ldsT[wv][buf][0] + troff;
        u32x2 r00, r01, r10, r11;
        asm volatile(
            "ds_read_b64_tr_b16 %0, %4\n\t"
            "ds_read_b64_tr_b16 %1, %4 offset:512\n\t"
            "ds_read_b64_tr_b16 %2, %4 offset:1024\n\t"
            "ds_read_b64_tr_b16 %3, %4 offset:1536\n\t"
            "s_waitcnt lgkmcnt(0)"
            : "=&v"(r00), "=&v"(r01), "=&v"(r10), "=&v"(r11)
            : "v"(base)
            : "memory");
        __builtin_amdgcn_sched_barrier(0);   // rule #18: pin MFMA after wait

        uint4 a0q = make_uint4(r00[0], r00[1], r01[0], r01[1]);
        uint4 a1q = make_uint4(r10[0], r10[1], r11[0], r11[1]);
        bf16x8 am0 = *(bf16x8*)&a0q;
        bf16x8 am1 = *(bf16x8*)&a1q;
        acc0 = __builtin_amdgcn_mfma_f32_16x16x32_bf16(am0, bm, acc0, 0, 0, 0);
        acc1 = __builtin_amdgcn_mfma_f32_16x16x32_bf16(am1, bm, acc1, 0, 0, 0);

        // ---- write next round's tile (vmcnt gated by compiler) ----
        WRITE((r + 1) & 1, Q0, Q1);
        mq = mqn;
    }

    // ---- epilogue in C-layout: lane's 4 regs = 4 consecutive dims of dst ----
    int dst = d0 + l15;
    bool dok = dst < n_dst;
    int dc = min(dst, n_dst - 1);
    int lt  = last_tok[dc];
    int nch = seg_end[dc] - seg_start[dc] - 1;
    bool gate = nch > 0;
    int q = (l >> 4) * 4;                       // dim quad within 16-half
    ushort4 lm0 = *(const ushort4*)(esl + (size_t)lt * 32 + q);
    ushort4 lm1 = *(const ushort4*)(esl + (size_t)lt * 32 + 16 + q);
    float4 b0 = *(const float4*)(bvec + sl * 32 + q);
    float4 b1 = *(const float4*)(bvec + sl * 32 + 16 + q);
    ushort4 o0, o1;
    o0.x = f2bu(bu2f(lm0.x) + (gate ? fmaxf(acc0[0] + b0.x, 0.f) : 0.f));
    o0.y = f2bu(bu2f(lm0.y) + (gate ? fmaxf(acc0[1] + b0.y, 0.f) : 0.f));
    o0.z = f2bu(bu2f(lm0.z) + (gate ? fmaxf(acc0[2] + b0.z, 0.f) : 0.f));
    o0.w = f2bu(bu2f(lm0.w) + (gate ? fmaxf(acc0[3] + b0.w, 0.f) : 0.f));
    o1.x = f2bu(bu2f(lm1.x) + (gate ? fmaxf(acc1[0] + b1.x, 0.f) : 0.f));
    o1.y = f2bu(bu2f(lm1.y) + (gate ? fmaxf(acc1[1] + b1.y, 0.f) : 0.f));
    o1.z = f2bu(bu2f(lm1.z) + (gate ? fmaxf(acc1[2] + b1.z, 0.f) : 0.f));
    o1.w = f2bu(bu2f(lm1.w) + (gate ? fmaxf(acc1[3] + b1.w, 0.f) : 0.f));
    if (dok) {
        __hip_bfloat16* fb = ftb + (size_t)sl * n_dst * 32 + (size_t)dst * 32;
        *(ushort4*)(fb + q)      = o0;
        *(ushort4*)(fb + 16 + q) = o1;
    }
}

// ---------------------------------------------------------------------------
// Kernel 4: classifier GEMM. 64-row blocks, Wcfrag staged via straight
// 32KB copies (2 phases). ftb is slice-major [8][M][32]; k0 == slice.
// ---------------------------------------------------------------------------
__global__ __launch_bounds__(256, 4) void cls_mfma(
    const __hip_bfloat16* __restrict__ ftb,     // [8][M][32] bf16
    const __hip_bfloat16* __restrict__ Wcfrag,  // 64 groups x 512
    const float* __restrict__ bc,               // [104]
    float* __restrict__ out,                    // [M,104]
    int M)
{
    __shared__ __hip_bfloat16 lds[32 * 512];    // 32KB
    const int t    = threadIdx.x;
    const int lane = t & 63;
    const int w    = t >> 6;
    const int quad = lane >> 4;
    const int l16  = lane & 15;
    const int mw   = blockIdx.x * 64 + w * 16;

    int mrow = min(mw + l16, M - 1);
    bf16x8 ffrag[8];
#pragma unroll
    for (int k0 = 0; k0 < 8; ++k0)
        ffrag[k0] = *(const bf16x8*)(ftb + (size_t)k0 * M * 32 +
                                     (size_t)mrow * 32 + quad * 8);

    f32x4 acc[8];
#pragma unroll
    for (int nt = 0; nt < 8; ++nt) acc[nt] = (f32x4){0.f,0.f,0.f,0.f};

    for (int p = 0; p < 2; ++p) {
        if (p) __syncthreads();
#pragma unroll
        for (int it = 0; it < 8; ++it) {
            int idx = it * 256 + t;
            *(uint4*)(lds + (size_t)idx * 8) =
                *(const uint4*)(Wcfrag + (size_t)p * 16384 + (size_t)idx * 8);
        }
        __syncthreads();
#pragma unroll
        for (int kl = 0; kl < 4; ++kl) {
            int k0 = p * 4 + kl;
#pragma unroll
            for (int nt = 0; nt < 8; ++nt) {
                bf16x8 wf = *(const bf16x8*)(lds + (kl * 8 + nt) * 512 + lane * 8);
                acc[nt] = __builtin_amdgcn_mfma_f32_16x16x32_bf16(wf, ffrag[k0], acc[nt], 0, 0, 0);
            }
        }
    }

    int m = mw + l16;
    if (m < M) {
#pragma unroll
        for (int nt = 0; nt < 8; ++nt) {
            int c0 = nt * 16 + quad * 4;
            if (c0 <= 100) {
                float4 bia = *(const float4*)(bc + c0);
                float4 o;
                o.x = acc[nt][0] + bia.x;
                o.y = acc[nt][1] + bia.y;
                o.z = acc[nt][2] + bia.z;
                o.w = acc[nt][3] + bia.w;
                *(float4*)(out + (size_t)m * CC + c0) = o;
            }
        }
    }
}

// ---------------------------------------------------------------------------
extern "C" void kernel_launch(void* const* d_in, const int* in_sizes, int n_in,
                              void* d_out, int out_size, void* d_ws, size_t ws_size,
                              hipStream_t stream)
{
    const float* emb      = (const float*)d_in[0];
    const float* W        = (const float*)d_in[1];
    const float* bvec     = (const float*)d_in[2];
    const float* Wc       = (const float*)d_in[3];
    const float* bc       = (const float*)d_in[4];
    const int*   token_id = (const int*)d_in[5];
    const int*   src_idx  = (const int*)d_in[6];
    const int*   dst_idx  = (const int*)d_in[7];
    float*       out      = (float*)d_out;

    const int E     = in_sizes[6];
    const int Vemb  = in_sizes[0] / DD;
    const int n_dst = out_size / CC;
    (void)n_in; (void)ws_size;

    char* ws = (char*)d_ws;
    size_t off = 0;
    auto alloc = [&](size_t bytes) {
        void* p = ws + off;
        off = (off + bytes + 255) & ~(size_t)255;
        return p;
    };
    const int ngroups = (n_dst + 15) / 16;
    const size_t mask_slots = (size_t)(E >> 5) + ngroups + 2;
    int* seg_start = (int*)alloc((size_t)n_dst * sizeof(int));
    int* seg_end   = (int*)alloc((size_t)n_dst * sizeof(int));
    int* last_tok  = (int*)alloc((size_t)n_dst * sizeof(int));
    int* etp       = (int*)alloc((size_t)E * sizeof(int));
    __hip_bfloat16* embb   = (__hip_bfloat16*)alloc((size_t)Vemb * DD * 2);
    __hip_bfloat16* Webuf  = (__hip_bfloat16*)alloc((size_t)Vemb * DD * 2);
    __hip_bfloat16* ftb    = (__hip_bfloat16*)alloc((size_t)n_dst * DD * 2);
    __hip_bfloat16* Wfrag  = (__hip_bfloat16*)alloc((size_t)128 * 512 * 2);
    __hip_bfloat16* Wcfrag = (__hip_bfloat16*)alloc((size_t)64 * 512 * 2);
    uint4* maskbuf = (uint4*)alloc(mask_slots * 1024);

    const int PB = (E + 255) / 256;
    const int we_blocks  = (Vemb + 63) / 64;
    const int seg_blocks = NSL * ((ngroups + 3) / 4);
    const int cls_blocks = (n_dst + 63) / 64;

    prep_all<<<PB + 48, 256, 0, stream>>>(
        token_id, src_idx, dst_idx, seg_start, seg_end, etp, last_tok, E, PB,
        W, Wc, Wfrag, Wcfrag);
    mask_build<<<ngroups, 256, 0, stream>>>(
        etp, seg_start, seg_end, maskbuf, n_dst);
    we_gemm<<<we_blocks, 256, 0, stream>>>(
        emb, Wfrag, Webuf, embb, Vemb);
    seg_mfma<<<seg_blocks, 256, 0, stream>>>(
        Webuf, embb, etp, seg_start, seg_end, last_tok, maskbuf, bvec, ftb,
        n_dst, Vemb);
    cls_mfma<<<cls_blocks, 256, 0, stream>>>(
        ftb, Wcfrag, bc, out, n_dst);
}

// Round 10
// 187.535 us; speedup vs baseline: 1.3727x; 1.3727x over previous
//
#include <hip/hip_runtime.h>
#include <hip/hip_bf16.h>

#define DD 256
#define CC 104
#define NSL 8      // feature slices: 8 x 32 dims (64B) — one slice per XCD

typedef __bf16 bf16x8 __attribute__((ext_vector_type(8)));
typedef float  f32x4  __attribute__((ext_vector_type(4)));

__device__ inline float bu2f(unsigned short u) {
    return __uint_as_float(((unsigned)u) << 16);
}
__device__ inline unsigned short f2bu(float f) {
    __hip_bfloat16 h = __float2bfloat16(f);
    return *reinterpret_cast<unsigned short*>(&h);
}

// ---------------------------------------------------------------------------
// Kernel 1: prep — per-edge boundaries/tokens/last-token + W,Wc -> bf16 frags.
// Fragment layout (g = group, s = lane, j<8):
//   frag[g*512 + s*8 + j] = Wsrc[(nt*16 + (s&15))*256 + k0*32 + (s>>4)*8 + j]
//   W: g = k0*16 + nt (8 x 16);  Wc: g = k0*8 + nt (8 x 8, rows padded to 128)
// ---------------------------------------------------------------------------
__global__ void prep_all(
    const int* __restrict__ token_id,
    const int* __restrict__ src_idx,
    const int* __restrict__ dst_idx,
    int* __restrict__ seg_start,
    int* __restrict__ seg_end,
    int* __restrict__ edge_tok,
    int* __restrict__ last_tok,
    int E, int PB,
    const float* __restrict__ W,
    const float* __restrict__ Wc,
    __hip_bfloat16* __restrict__ Wfrag,
    __hip_bfloat16* __restrict__ Wcfrag)
{
    const int b = blockIdx.x;
    const int t = threadIdx.x;
    if (b < PB) {
        int e = b * 256 + t;
        if (e >= E) return;
        int d = dst_idx[e];
        int tok = token_id[src_idx[e]];
        edge_tok[e] = tok;
        if (e == 0 || dst_idx[e - 1] != d) seg_start[d] = e;
        if (e == E - 1 || dst_idx[e + 1] != d) { seg_end[d] = e + 1; last_tok[d] = tok; }
        return;
    }
    if (b < PB + 32) {                      // W fragment reorder
        int idx  = (b - PB) * 256 + t;      // 0..8191
        int lane = idx & 63, g = idx >> 6;  // g = k0*16 + nt
        int nt = g & 15, k0 = g >> 4;
        int r = nt * 16 + (lane & 15);
        int c = k0 * 32 + (lane >> 4) * 8;
        const float* src = W + (size_t)r * DD + c;
        float4 v0 = *(const float4*)(src);
        float4 v1 = *(const float4*)(src + 4);
        uint4 pk;
        pk.x = (unsigned)f2bu(v0.x) | ((unsigned)f2bu(v0.y) << 16);
        pk.y = (unsigned)f2bu(v0.z) | ((unsigned)f2bu(v0.w) << 16);
        pk.z = (unsigned)f2bu(v1.x) | ((unsigned)f2bu(v1.y) << 16);
        pk.w = (unsigned)f2bu(v1.z) | ((unsigned)f2bu(v1.w) << 16);
        *(uint4*)(Wfrag + (size_t)idx * 8) = pk;
        return;
    }
    {                                       // Wc fragment reorder (padded)
        int idx  = (b - PB - 32) * 256 + t; // 0..4095
        int lane = idx & 63, g = idx >> 6;  // g = k0*8 + nt
        int nt = g & 7, k0 = g >> 3;
        int r = nt * 16 + (lane & 15);      // 0..127
        int c = k0 * 32 + (lane >> 4) * 8;
        float4 v0 = make_float4(0.f,0.f,0.f,0.f);
        float4 v1 = make_float4(0.f,0.f,0.f,0.f);
        if (r < CC) {
            const float* src = Wc + (size_t)r * DD + c;
            v0 = *(const float4*)(src);
            v1 = *(const float4*)(src + 4);
        }
        uint4 pk;
        pk.x = (unsigned)f2bu(v0.x) | ((unsigned)f2bu(v0.y) << 16);
        pk.y = (unsigned)f2bu(v0.z) | ((unsigned)f2bu(v0.w) << 16);
        pk.z = (unsigned)f2bu(v1.x) | ((unsigned)f2bu(v1.y) << 16);
        pk.w = (unsigned)f2bu(v1.z) | ((unsigned)f2bu(v1.w) << 16);
        *(uint4*)(Wcfrag + (size_t)idx * 8) = pk;
    }
}

// ---------------------------------------------------------------------------
// Kernel 2: We = emb @ W^T for ALL tokens (dense streaming MFMA GEMM).
// Webuf and embb written SLICE-MAJOR: [slice=dim/32][V][32 dims] so each
// XCD's L2 can keep exactly its 3.2MB slice resident during the gather.
// ---------------------------------------------------------------------------
__global__ __launch_bounds__(256, 3) void we_gemm(
    const float* __restrict__ emb,             // [V,256] fp32
    const __hip_bfloat16* __restrict__ Wfrag,  // 128 groups x 512
    __hip_bfloat16* __restrict__ Webuf,        // [8][V][32] bf16 out
    __hip_bfloat16* __restrict__ embb,         // [8][V][32] bf16 out
    int V)
{
    __shared__ __hip_bfloat16 lds[32 * 512];   // 32KB
    const int t    = threadIdx.x;
    const int lane = t & 63;
    const int w    = t >> 6;
    const int quad = lane >> 4;
    const int l16  = lane & 15;
    const int mrow = blockIdx.x * 64 + w * 16 + l16;
    const int row  = min(mrow, V - 1);

    // stream emb row fp32 -> bf16 frags (+ embb slice-major side-write)
    bf16x8 bfrag[8];
#pragma unroll
    for (int k0 = 0; k0 < 8; ++k0) {
        const float* src = emb + (size_t)row * DD + k0 * 32 + quad * 8;
        float4 v0 = *(const float4*)(src);
        float4 v1 = *(const float4*)(src + 4);
        uint4 pk;
        pk.x = (unsigned)f2bu(v0.x) | ((unsigned)f2bu(v0.y) << 16);
        pk.y = (unsigned)f2bu(v0.z) | ((unsigned)f2bu(v0.w) << 16);
        pk.z = (unsigned)f2bu(v1.x) | ((unsigned)f2bu(v1.y) << 16);
        pk.w = (unsigned)f2bu(v1.z) | ((unsigned)f2bu(v1.w) << 16);
        bfrag[k0] = *(bf16x8*)&pk;
        if (mrow < V)   // slice k0, chunk quad*8 within slice
            *(uint4*)(embb + (size_t)k0 * V * 32 + (size_t)row * 32 + quad * 8) = pk;
    }

    f32x4 acc[16];
#pragma unroll
    for (int nt = 0; nt < 16; ++nt) acc[nt] = (f32x4){0.f,0.f,0.f,0.f};

    for (int p = 0; p < 4; ++p) {
        if (p) __syncthreads();
        // straight-copy groups [32p, 32p+32): 32KB
#pragma unroll
        for (int it = 0; it < 8; ++it) {
            int idx = it * 256 + t;
            *(uint4*)(lds + (size_t)idx * 8) =
                *(const uint4*)(Wfrag + (size_t)p * 16384 + (size_t)idx * 8);
        }
        __syncthreads();
#pragma unroll
        for (int kl = 0; kl < 2; ++kl) {
            int k0 = p * 2 + kl;
#pragma unroll
            for (int nt = 0; nt < 16; ++nt) {
                bf16x8 wf = *(const bf16x8*)(lds + (kl * 16 + nt) * 512 + lane * 8);
                acc[nt] = __builtin_amdgcn_mfma_f32_16x16x32_bf16(wf, bfrag[k0], acc[nt], 0, 0, 0);
            }
        }
    }

    if (mrow < V) {
#pragma unroll
        for (int nt = 0; nt < 16; ++nt) {
            int c0 = nt * 16 + quad * 4;    // starting dim of this 4-dim piece
            ushort4 o;
            o.x = f2bu(acc[nt][0]);
            o.y = f2bu(acc[nt][1]);
            o.z = f2bu(acc[nt][2]);
            o.w = f2bu(acc[nt][3]);
            *(ushort4*)(Webuf + (size_t)(c0 >> 5) * V * 32 +
                        (size_t)mrow * 32 + (c0 & 31)) = o;
        }
    }
}

// ---------------------------------------------------------------------------
// Kernel 3: segment sum + rnn epilogue, XCD-SLICED + BATCHED (R13 — best).
// R12 proved slicing fixes the traffic wall (FETCH 156->63.6MB); R13 batches
// the child loop 8-deep: per trip, 8 independent token loads -> 8 clamped
// gathers (all in flight) -> sched_barrier(0) -> EXEC-masked accumulate.
// R14-R16 (mask-MFMA, dbuf+tr-read, precomputed masks) did NOT beat this:
// nine structures land 52-56us with no pipe saturated -> per-CU outstanding-
// miss cap on the random-gather path (~7.8TB/s effective L2->CU). This is
// the measured-best variant (185.8us total).
// ---------------------------------------------------------------------------
__global__ __launch_bounds__(256, 6) void seg_rnn_kernel(
    const __hip_bfloat16* __restrict__ Webuf,   // [8][V][32]
    const __hip_bfloat16* __restrict__ embb,    // [8][V][32]
    const int* __restrict__ edge_tok,
    const int* __restrict__ seg_start,
    const int* __restrict__ seg_end,
    const int* __restrict__ last_tok,
    const float* __restrict__ bvec,
    __hip_bfloat16* __restrict__ ftb,           // [8][n_dst][32]
    int n_dst, int V)
{
    const int bid  = blockIdx.x;
    const int sl   = bid & 7;                   // slice == XCD (round-robin)
    const int g    = bid >> 3;                  // dst-group of 64
    const int t    = threadIdx.x;
    const int wv   = t >> 6;
    const int lane = t & 63;
    const int grp  = lane >> 2;                 // dst within wave [0,16)
    const int c    = lane & 3;                  // 16B chunk within 64B slice

    int d = g * 64 + wv * 16 + grp;
    bool dok = d < n_dst;
    int dc = dok ? d : n_dst - 1;
    int s  = seg_start[dc];
    int e  = seg_end[dc];
    int lt = last_tok[dc];
    int n  = dok ? (e - 1 - s) : 0;             // children to sum (deg-1)
    int nm1 = n - 1;

    const __hip_bfloat16* wsl = Webuf + (size_t)sl * V * 32;
    const __hip_bfloat16* esl = embb  + (size_t)sl * V * 32;
    // last-message slice read (overlaps the loop below)
    uint4 lm = *(const uint4*)(esl + (size_t)lt * 32 + c * 8);

    float acc[8] = {0.f,0.f,0.f,0.f,0.f,0.f,0.f,0.f};

    for (int j0 = 0; __any(j0 < n); j0 += 8) {
        // 8 independent token loads (4 lanes/group load same addr: broadcast)
        int tk[8];
#pragma unroll
        for (int i = 0; i < 8; ++i) {
            int idx = j0 + i;
            idx = idx < nm1 ? idx : nm1;    // clamp high -> valid child
            idx = idx > 0 ? idx : 0;        // clamp low (n==0 -> nm1==-1)
            tk[i] = edge_tok[s + idx];
        }
        // 8 gathers, all in flight; clamped rows re-read a cached line
        uint4 u[8];
#pragma unroll
        for (int i = 0; i < 8; ++i)
            u[i] = *(const uint4*)(wsl + (size_t)tk[i] * 32 + c * 8);
        __builtin_amdgcn_sched_barrier(0);
#pragma unroll
        for (int i = 0; i < 8; ++i) {
            if (j0 + i < n) {               // per-group-uniform, EXEC-masked
                const unsigned* p = (const unsigned*)&u[i];
#pragma unroll
                for (int k = 0; k < 4; ++k) {
                    acc[2*k]   += __uint_as_float(p[k] << 16);
                    acc[2*k+1] += __uint_as_float(p[k] & 0xffff0000u);
                }
            }
        }
    }

    bool gate = n > 0;
    // epilogue: each lane owns 8 dims of its dst — no cross-lane reduce
    float4 b0 = *(const float4*)(bvec + sl * 32 + c * 8);
    float4 b1 = *(const float4*)(bvec + sl * 32 + c * 8 + 4);
    float bl[8] = {b0.x, b0.y, b0.z, b0.w, b1.x, b1.y, b1.z, b1.w};
    const unsigned* lmd = (const unsigned*)&lm;
    uint4 o;
    unsigned* od = (unsigned*)&o;
#pragma unroll
    for (int k = 0; k < 4; ++k) {
        float lo = __uint_as_float(lmd[k] << 16);
        float hi = __uint_as_float(lmd[k] & 0xffff0000u);
        float v0 = lo + (gate ? fmaxf(acc[2*k]   + bl[2*k],   0.f) : 0.f);
        float v1 = hi + (gate ? fmaxf(acc[2*k+1] + bl[2*k+1], 0.f) : 0.f);
        od[k] = (unsigned)f2bu(v0) | ((unsigned)f2bu(v1) << 16);
    }
    if (dok)    // wave stores 16 dsts x 64B = 1KB contiguous per slice
        *(uint4*)(ftb + (size_t)sl * n_dst * 32 + (size_t)d * 32 + c * 8) = o;
}

// ---------------------------------------------------------------------------
// Kernel 4: classifier GEMM. 64-row blocks, Wcfrag staged via straight
// 32KB copies (2 phases). ftb is slice-major [8][M][32]; k0 == slice.
// ---------------------------------------------------------------------------
__global__ __launch_bounds__(256, 4) void cls_mfma(
    const __hip_bfloat16* __restrict__ ftb,     // [8][M][32] bf16
    const __hip_bfloat16* __restrict__ Wcfrag,  // 64 groups x 512
    const float* __restrict__ bc,               // [104]
    float* __restrict__ out,                    // [M,104]
    int M)
{
    __shared__ __hip_bfloat16 lds[32 * 512];    // 32KB
    const int t    = threadIdx.x;
    const int lane = t & 63;
    const int w    = t >> 6;
    const int quad = lane >> 4;
    const int l16  = lane & 15;
    const int mw   = blockIdx.x * 64 + w * 16;

    int mrow = min(mw + l16, M - 1);
    bf16x8 ffrag[8];
#pragma unroll
    for (int k0 = 0; k0 < 8; ++k0)
        ffrag[k0] = *(const bf16x8*)(ftb + (size_t)k0 * M * 32 +
                                     (size_t)mrow * 32 + quad * 8);

    f32x4 acc[8];
#pragma unroll
    for (int nt = 0; nt < 8; ++nt) acc[nt] = (f32x4){0.f,0.f,0.f,0.f};

    for (int p = 0; p < 2; ++p) {
        if (p) __syncthreads();
#pragma unroll
        for (int it = 0; it < 8; ++it) {
            int idx = it * 256 + t;
            *(uint4*)(lds + (size_t)idx * 8) =
                *(const uint4*)(Wcfrag + (size_t)p * 16384 + (size_t)idx * 8);
        }
        __syncthreads();
#pragma unroll
        for (int kl = 0; kl < 4; ++kl) {
            int k0 = p * 4 + kl;
#pragma unroll
            for (int nt = 0; nt < 8; ++nt) {
                bf16x8 wf = *(const bf16x8*)(lds + (kl * 8 + nt) * 512 + lane * 8);
                acc[nt] = __builtin_amdgcn_mfma_f32_16x16x32_bf16(wf, ffrag[k0], acc[nt], 0, 0, 0);
            }
        }
    }

    int m = mw + l16;
    if (m < M) {
#pragma unroll
        for (int nt = 0; nt < 8; ++nt) {
            int c0 = nt * 16 + quad * 4;
            if (c0 <= 100) {
                float4 bia = *(const float4*)(bc + c0);
                float4 o;
                o.x = acc[nt][0] + bia.x;
                o.y = acc[nt][1] + bia.y;
                o.z = acc[nt][2] + bia.z;
                o.w = acc[nt][3] + bia.w;
                *(float4*)(out + (size_t)m * CC + c0) = o;
            }
        }
    }
}

// ---------------------------------------------------------------------------
extern "C" void kernel_launch(void* const* d_in, const int* in_sizes, int n_in,
                              void* d_out, int out_size, void* d_ws, size_t ws_size,
                              hipStream_t stream)
{
    const float* emb      = (const float*)d_in[0];
    const float* W        = (const float*)d_in[1];
    const float* bvec     = (const float*)d_in[2];
    const float* Wc       = (const float*)d_in[3];
    const float* bc       = (const float*)d_in[4];
    const int*   token_id = (const int*)d_in[5];
    const int*   src_idx  = (const int*)d_in[6];
    const int*   dst_idx  = (const int*)d_in[7];
    float*       out      = (float*)d_out;

    const int E     = in_sizes[6];
    const int Vemb  = in_sizes[0] / DD;
    const int n_dst = out_size / CC;
    (void)n_in; (void)ws_size;

    char* ws = (char*)d_ws;
    size_t off = 0;
    auto alloc = [&](size_t bytes) {
        void* p = ws + off;
        off = (off + bytes + 255) & ~(size_t)255;
        return p;
    };
    int* seg_start = (int*)alloc((size_t)n_dst * sizeof(int));
    int* seg_end   = (int*)alloc((size_t)n_dst * sizeof(int));
    int* last_tok  = (int*)alloc((size_t)n_dst * sizeof(int));
    int* edge_tok  = (int*)alloc((size_t)E * sizeof(int));
    __hip_bfloat16* embb   = (__hip_bfloat16*)alloc((size_t)Vemb * DD * 2);
    __hip_bfloat16* Webuf  = (__hip_bfloat16*)alloc((size_t)Vemb * DD * 2);
    __hip_bfloat16* ftb    = (__hip_bfloat16*)alloc((size_t)n_dst * DD * 2);
    __hip_bfloat16* Wfrag  = (__hip_bfloat16*)alloc((size_t)128 * 512 * 2);
    __hip_bfloat16* Wcfrag = (__hip_bfloat16*)alloc((size_t)64 * 512 * 2);

    const int PB = (E + 255) / 256;
    const int we_blocks  = (Vemb + 63) / 64;
    const int seg_blocks = NSL * ((n_dst + 63) / 64);
    const int cls_blocks = (n_dst + 63) / 64;

    prep_all<<<PB + 48, 256, 0, stream>>>(
        token_id, src_idx, dst_idx, seg_start, seg_end, edge_tok, last_tok, E, PB,
        W, Wc, Wfrag, Wcfrag);
    we_gemm<<<we_blocks, 256, 0, stream>>>(
        emb, Wfrag, Webuf, embb, Vemb);
    seg_rnn_kernel<<<seg_blocks, 256, 0, stream>>>(
        Webuf, embb, edge_tok, seg_start, seg_end, last_tok, bvec, ftb,
        n_dst, Vemb);
    cls_mfma<<<cls_blocks, 256, 0, stream>>>(
        ftb, Wcfrag, bc, out, n_dst);
}